// Round 1
// baseline (50.383 us; speedup 1.0000x reference)
//
#include <hip/hip_runtime.h>
#include <math.h>

#define NB 16
#define NQ 900
#define NC 80
#define EPSV 1e-7f
#define IOU_THR 0.1f

// ---------------- K1: per-(b, student q) argmax IoU over 900 teachers ----------------
// 4 lanes per student query split the teacher loop (225 each); teacher corners/areas in LDS.
__global__ __launch_bounds__(256) void k1_box(const float* __restrict__ s_boxes,
                                              const float* __restrict__ t_boxes,
                                              float* __restrict__ max_iou,
                                              int* __restrict__ max_idx,
                                              float* __restrict__ l1c0,
                                              float* __restrict__ giouc0)
{
    __shared__ float4 tcor[NQ];   // x1, x2, y1, y2
    __shared__ float  tarea[NQ];
    const int b = blockIdx.y;
    const float4* tb = (const float4*)(t_boxes + b * NQ * 4);
    for (int i = threadIdx.x; i < NQ; i += 256) {
        float4 t = tb[i];
        float hw = t.z * 0.5f, hh = t.w * 0.5f;
        tcor[i]  = make_float4(t.x - hw, t.x + hw, t.y - hh, t.y + hh);
        tarea[i] = t.z * t.w;
    }
    __syncthreads();

    const int sql = threadIdx.x >> 2;   // 0..63 student within block
    const int tc  = threadIdx.x & 3;    // teacher chunk 0..3
    const int sq  = blockIdx.x * 64 + sql;
    if (sq >= NQ) return;

    float4 sb = ((const float4*)(s_boxes + b * NQ * 4))[sq];
    float shw = sb.z * 0.5f, shh = sb.w * 0.5f;
    float sx1 = sb.x - shw, sx2 = sb.x + shw;
    float sy1 = sb.y - shh, sy2 = sb.y + shh;
    float sarea = sb.z * sb.w;

    float best = -1.0f; int bidx = 0;
    const int t0i = tc * 225;
    #pragma unroll 5
    for (int i = 0; i < 225; ++i) {
        int t = t0i + i;
        float4 c = tcor[t];
        float iw = fminf(sx2, c.y) - fmaxf(sx1, c.x);
        float ih = fminf(sy2, c.w) - fmaxf(sy1, c.z);
        float inter = fmaxf(iw, 0.0f) * fmaxf(ih, 0.0f);
        float uni = sarea + tarea[t] - inter + EPSV;
        float iou = inter * __frcp_rn(uni);
        if (iou > best) { best = iou; bidx = t; }   // strictly greater -> first index wins
    }
    // combine the 4 teacher chunks (adjacent lanes); ties -> lower teacher index
    for (int m = 1; m <= 2; m <<= 1) {
        float ov = __shfl_xor(best, m, 64);
        int   oi = __shfl_xor(bidx, m, 64);
        if (ov > best || (ov == best && oi < bidx)) { best = ov; bidx = oi; }
    }
    if (tc == 0) {
        int o = b * NQ + sq;
        max_iou[o] = best;
        max_idx[o] = bidx;
        // L1 and (1 - GIoU) vs teacher box 0, exact div to match ref closely
        float4 t0 = tb[0];
        float4 c  = tcor[0];
        float iw = fminf(sx2, c.y) - fmaxf(sx1, c.x);
        float ih = fminf(sy2, c.w) - fmaxf(sy1, c.z);
        float inter = fmaxf(iw, 0.0f) * fmaxf(ih, 0.0f);
        float uni = sarea + tarea[0] - inter + EPSV;
        float iou = inter / uni;
        float cw = fmaxf(sx2, c.y) - fminf(sx1, c.x);
        float ch = fmaxf(sy2, c.w) - fminf(sy1, c.z);
        float carea = cw * ch + EPSV;
        float giou = iou - (carea - uni) / carea;
        giouc0[o] = 1.0f - giou;
        l1c0[o] = fabsf(sb.x - t0.x) + fabsf(sb.y - t0.y) +
                  fabsf(sb.z - t0.z) + fabsf(sb.w - t0.w);
    }
}

// ---------------- K2: wave-per-row conf bit + BCE (gather teacher row from batch 0) ----
__global__ __launch_bounds__(256) void k2_cls(const float* __restrict__ s_logits,
                                              const float* __restrict__ t_logits,
                                              const int* __restrict__ max_idx,
                                              float* __restrict__ bce_part,
                                              int* __restrict__ conf_part,
                                              int* __restrict__ conf0)
{
    __shared__ float sbce[4];
    __shared__ int   sconf[4];
    const int w    = threadIdx.x >> 6;
    const int lane = threadIdx.x & 63;
    const int row  = blockIdx.x * 4 + w;
    const int j    = max_idx[row];             // flat idx in [0,900) -> batch-0 row (ref quirk)
    const float* srow = s_logits + row * NC;
    const float* trow = t_logits + row * NC;
    const float* grow = t_logits + j * NC;

    float s0 = srow[lane];
    float t0 = trow[lane];
    float g0 = grow[lane];
    float bce = fmaxf(s0, 0.f) + log1pf(__expf(-fabsf(s0)))
              - s0 * (1.0f / (1.0f + __expf(-g0)));
    float tmax = t0;
    if (lane < NC - 64) {
        float s1 = srow[lane + 64];
        float t1 = trow[lane + 64];
        float g1 = grow[lane + 64];
        bce += fmaxf(s1, 0.f) + log1pf(__expf(-fabsf(s1)))
             - s1 * (1.0f / (1.0f + __expf(-g1)));
        tmax = fmaxf(tmax, t1);
    }
    for (int m = 32; m >= 1; m >>= 1) {
        bce  += __shfl_xor(bce, m, 64);
        tmax  = fmaxf(tmax, __shfl_xor(tmax, m, 64));
    }
    if (lane == 0) {
        int cbit = (1.0f / (1.0f + __expf(-tmax)) > 0.2f) ? 1 : 0;
        sbce[w]  = bce * (1.0f / (float)NC);
        sconf[w] = cbit;
        int q = row % NQ;
        if (q == 0) conf0[row / NQ] = cbit;    // conf[b, 0]
    }
    __syncthreads();
    if (threadIdx.x == 0) {
        bce_part[blockIdx.x]  = sbce[0] + sbce[1] + sbce[2] + sbce[3];
        conf_part[blockIdx.x] = sconf[0] | sconf[1] | sconf[2] | sconf[3];
    }
}

// ---------------- K3: single block — partial sums, flag-gated gather sums, finalize ----
__global__ __launch_bounds__(1024) void k3_final(const float* __restrict__ bce_part,
                                                 const int* __restrict__ conf_part,
                                                 const int* __restrict__ conf0,
                                                 const float* __restrict__ max_iou,
                                                 const int* __restrict__ max_idx,
                                                 const float* __restrict__ l1c0,
                                                 const float* __restrict__ giouc0,
                                                 const int* __restrict__ tn_p,
                                                 float* __restrict__ out)
{
    float bces = 0.f; int anyc = 0;
    for (int i = threadIdx.x; i < 3600; i += 1024) {
        bces += bce_part[i];
        anyc |= conf_part[i];
    }
    float l1s = 0.f, gs = 0.f;
    for (int i = threadIdx.x; i < NB * NQ; i += 1024) {
        int b = i / NQ;
        int j = max_idx[i];
        float mi = max_iou[b * NQ + j];        // student-indexed gather (ref quirk)
        if (mi > IOU_THR && conf0[b]) {
            l1s += l1c0[b * NQ + j];
            gs  += giouc0[b * NQ + j];
        }
    }
    __shared__ float rb[16], rl[16], rg[16];
    __shared__ int ra[16];
    int w = threadIdx.x >> 6, lane = threadIdx.x & 63;
    for (int m = 32; m >= 1; m >>= 1) {
        bces += __shfl_xor(bces, m, 64);
        l1s  += __shfl_xor(l1s, m, 64);
        gs   += __shfl_xor(gs, m, 64);
        anyc |= __shfl_xor(anyc, m, 64);
    }
    if (lane == 0) { rb[w] = bces; rl[w] = l1s; rg[w] = gs; ra[w] = anyc; }
    __syncthreads();
    if (threadIdx.x == 0) {
        float sb = 0.f, sl = 0.f, sg = 0.f; int sa = 0;
        for (int k = 0; k < 16; ++k) { sb += rb[k]; sl += rl[k]; sg += rg[k]; sa |= ra[k]; }
        float tn = (float)tn_p[0];
        float loss = (5.0f * sl + 2.0f * sg + sb) / tn;
        out[0] = sa ? loss : 0.0f;
    }
}

extern "C" void kernel_launch(void* const* d_in, const int* in_sizes, int n_in,
                              void* d_out, int out_size, void* d_ws, size_t ws_size,
                              hipStream_t stream) {
    const float* s_logits = (const float*)d_in[0];
    const float* s_boxes  = (const float*)d_in[1];
    const float* t_logits = (const float*)d_in[2];
    const float* t_boxes  = (const float*)d_in[3];
    const int*   tn       = (const int*)d_in[4];
    float* out = (float*)d_out;

    char* ws = (char*)d_ws;
    float* bce_part  = (float*)(ws);            // 3600 f32
    int*   conf_part = (int*)(ws + 14400);      // 3600 i32
    int*   conf0     = (int*)(ws + 28800);      // 16 i32
    float* max_iou   = (float*)(ws + 28864);    // 14400 f32
    int*   max_idx   = (int*)(ws + 86464);      // 14400 i32
    float* l1c0      = (float*)(ws + 144064);   // 14400 f32
    float* giouc0    = (float*)(ws + 201664);   // 14400 f32

    k1_box<<<dim3(15, 16), 256, 0, stream>>>(s_boxes, t_boxes, max_iou, max_idx, l1c0, giouc0);
    k2_cls<<<3600, 256, 0, stream>>>(s_logits, t_logits, max_idx, bce_part, conf_part, conf0);
    k3_final<<<1, 1024, 0, stream>>>(bce_part, conf_part, conf0, max_iou, max_idx,
                                     l1c0, giouc0, tn, out);
}

// Round 2
// 34.969 us; speedup vs baseline: 1.4408x; 1.4408x over previous
//
#include <hip/hip_runtime.h>
#include <math.h>

#define NB 16
#define NQ 900
#define NC 80
#define EPSV 1e-7f
#define IOU_THR 0.1f

// ---------------- K1: per-(b, student q) argmax IoU over 900 teachers ----------------
// 8 lanes per student query, strided teacher loop (113 iters); teacher corners/areas in LDS.
// Also computes conf0[b] (sigmoid(max logits of teacher row 0) > 0.2) in block x==0.
__global__ __launch_bounds__(256) void k1_box(const float* __restrict__ s_boxes,
                                              const float* __restrict__ t_boxes,
                                              const float* __restrict__ t_logits,
                                              float* __restrict__ max_iou,
                                              int* __restrict__ max_idx,
                                              float* __restrict__ l1c0,
                                              float* __restrict__ giouc0,
                                              int* __restrict__ conf0)
{
    __shared__ float4 tcor[NQ];   // x1, x2, y1, y2
    __shared__ float  tarea[NQ];
    const int b = blockIdx.y;
    const float4* tb = (const float4*)(t_boxes + b * NQ * 4);
    for (int i = threadIdx.x; i < NQ; i += 256) {
        float4 t = tb[i];
        float hw = t.z * 0.5f, hh = t.w * 0.5f;
        tcor[i]  = make_float4(t.x - hw, t.x + hw, t.y - hh, t.y + hh);
        tarea[i] = t.z * t.w;
    }
    // conf0[b]: one wave of block x==0 (independent of LDS)
    if (blockIdx.x == 0 && threadIdx.x < 64) {
        const int lane = threadIdx.x;
        const float* tl = t_logits + b * NQ * NC;     // teacher row 0 of batch b
        float m = tl[lane];
        if (lane < NC - 64) m = fmaxf(m, tl[lane + 64]);
        for (int s = 32; s >= 1; s >>= 1) m = fmaxf(m, __shfl_xor(m, s, 64));
        if (lane == 0) conf0[b] = (1.0f / (1.0f + __expf(-m)) > 0.2f) ? 1 : 0;
    }
    __syncthreads();

    const int ql = threadIdx.x >> 3;   // 0..31 student within block
    const int tc = threadIdx.x & 7;    // teacher stride phase 0..7
    const int sq = blockIdx.x * 32 + ql;
    if (sq >= NQ) return;

    float4 sb = ((const float4*)(s_boxes + b * NQ * 4))[sq];
    float shw = sb.z * 0.5f, shh = sb.w * 0.5f;
    float sx1 = sb.x - shw, sx2 = sb.x + shw;
    float sy1 = sb.y - shh, sy2 = sb.y + shh;
    float sarea = sb.z * sb.w;

    float best = -1.0f; int bidx = 0;
    #pragma unroll 4
    for (int i = 0; i < 113; ++i) {
        int t = tc + (i << 3);
        if (t < NQ) {
            float4 c = tcor[t];
            float iw = fminf(sx2, c.y) - fmaxf(sx1, c.x);
            float ih = fminf(sy2, c.w) - fmaxf(sy1, c.z);
            float inter = fmaxf(iw, 0.0f) * fmaxf(ih, 0.0f);
            float uni = sarea + tarea[t] - inter + EPSV;
            float iou = inter * __frcp_rn(uni);
            if (iou > best) { best = iou; bidx = t; }  // strictly greater
        }
    }
    // combine 8 phases; ties -> lower teacher index (matches argmax first-occurrence)
    for (int m = 1; m <= 4; m <<= 1) {
        float ov = __shfl_xor(best, m, 64);
        int   oi = __shfl_xor(bidx, m, 64);
        if (ov > best || (ov == best && oi < bidx)) { best = ov; bidx = oi; }
    }
    if (tc == 0) {
        int o = b * NQ + sq;
        max_iou[o] = best;
        max_idx[o] = bidx;
        // L1 and (1 - GIoU) vs teacher box 0
        float4 t0 = tb[0];
        float4 c  = tcor[0];
        float iw = fminf(sx2, c.y) - fmaxf(sx1, c.x);
        float ih = fminf(sy2, c.w) - fmaxf(sy1, c.z);
        float inter = fmaxf(iw, 0.0f) * fmaxf(ih, 0.0f);
        float uni = sarea + tarea[0] - inter + EPSV;
        float iou = inter / uni;
        float cw = fmaxf(sx2, c.y) - fminf(sx1, c.x);
        float ch = fmaxf(sy2, c.w) - fminf(sy1, c.z);
        float carea = cw * ch + EPSV;
        float giou = iou - (carea - uni) / carea;
        giouc0[o] = 1.0f - giou;
        l1c0[o] = fabsf(sb.x - t0.x) + fabsf(sb.y - t0.y) +
                  fabsf(sb.z - t0.z) + fabsf(sb.w - t0.w);
    }
}

// ---------------- K2: wave handles 4 rows — conf bit, BCE, AND flag-gated l1/giou ------
__global__ __launch_bounds__(256) void k2_cls(const float* __restrict__ s_logits,
                                              const float* __restrict__ t_logits,
                                              const int* __restrict__ max_idx,
                                              const float* __restrict__ max_iou,
                                              const float* __restrict__ l1c0,
                                              const float* __restrict__ giouc0,
                                              const int* __restrict__ conf0,
                                              float4* __restrict__ partials)
{
    const int w    = threadIdx.x >> 6;
    const int lane = threadIdx.x & 63;
    float bcea = 0.f, l1a = 0.f, ga = 0.f; int confb = 0;
    const int base = blockIdx.x * 16 + w * 4;
    #pragma unroll
    for (int k = 0; k < 4; ++k) {
        int row = base + k;
        int j = max_idx[row];                 // flat idx in [0,900) -> batch-0 row (ref quirk)
        const float* srow = s_logits + row * NC;
        const float* trow = t_logits + row * NC;
        const float* grow = t_logits + j * NC;
        float s0 = srow[lane], t0 = trow[lane], g0 = grow[lane];
        float bce = fmaxf(s0, 0.f) + __logf(1.0f + __expf(-fabsf(s0)))
                  - s0 * __frcp_rn(1.0f + __expf(-g0));
        float tmax = t0;
        if (lane < NC - 64) {
            float s1 = srow[lane + 64], t1 = trow[lane + 64], g1 = grow[lane + 64];
            bce += fmaxf(s1, 0.f) + __logf(1.0f + __expf(-fabsf(s1)))
                 - s1 * __frcp_rn(1.0f + __expf(-g1));
            tmax = fmaxf(tmax, t1);
        }
        for (int m = 32; m >= 1; m >>= 1) {
            bce  += __shfl_xor(bce, m, 64);
            tmax  = fmaxf(tmax, __shfl_xor(tmax, m, 64));
        }
        if (lane == 0) {
            bcea += bce * (1.0f / (float)NC);
            confb |= (1.0f / (1.0f + __expf(-tmax)) > 0.2f) ? 1 : 0;
            int b = row / NQ;
            float mi = max_iou[b * NQ + j];   // student-indexed gather (ref quirk)
            if (mi > IOU_THR && conf0[b]) {
                l1a += l1c0[b * NQ + j];
                ga  += giouc0[b * NQ + j];
            }
        }
    }
    __shared__ float4 sp[4];
    if (lane == 0) sp[w] = make_float4(bcea, l1a, ga, (float)confb);
    __syncthreads();
    if (threadIdx.x == 0) {
        float4 a = sp[0], bq = sp[1], c = sp[2], d = sp[3];
        partials[blockIdx.x] = make_float4(a.x + bq.x + c.x + d.x,
                                           a.y + bq.y + c.y + d.y,
                                           a.z + bq.z + c.z + d.z,
                                           fmaxf(fmaxf(a.w, bq.w), fmaxf(c.w, d.w)));
    }
}

// ---------------- K3: trivial 900-element reduction + finalize ------------------------
__global__ __launch_bounds__(256) void k3_final(const float4* __restrict__ partials,
                                                const int* __restrict__ tn_p,
                                                float* __restrict__ out)
{
    float bs = 0.f, ls = 0.f, gs = 0.f, cs = 0.f;
    for (int i = threadIdx.x; i < 900; i += 256) {
        float4 p = partials[i];
        bs += p.x; ls += p.y; gs += p.z; cs = fmaxf(cs, p.w);
    }
    __shared__ float4 sp[4];
    const int w = threadIdx.x >> 6, lane = threadIdx.x & 63;
    for (int m = 32; m >= 1; m >>= 1) {
        bs += __shfl_xor(bs, m, 64);
        ls += __shfl_xor(ls, m, 64);
        gs += __shfl_xor(gs, m, 64);
        cs  = fmaxf(cs, __shfl_xor(cs, m, 64));
    }
    if (lane == 0) sp[w] = make_float4(bs, ls, gs, cs);
    __syncthreads();
    if (threadIdx.x == 0) {
        float4 a = sp[0], b = sp[1], c = sp[2], d = sp[3];
        float tn = (float)tn_p[0];
        float loss = (5.0f * (a.y + b.y + c.y + d.y) +
                      2.0f * (a.z + b.z + c.z + d.z) +
                             (a.x + b.x + c.x + d.x)) / tn;
        float any = fmaxf(fmaxf(a.w, b.w), fmaxf(c.w, d.w));
        out[0] = (any > 0.f) ? loss : 0.0f;
    }
}

extern "C" void kernel_launch(void* const* d_in, const int* in_sizes, int n_in,
                              void* d_out, int out_size, void* d_ws, size_t ws_size,
                              hipStream_t stream) {
    const float* s_logits = (const float*)d_in[0];
    const float* s_boxes  = (const float*)d_in[1];
    const float* t_logits = (const float*)d_in[2];
    const float* t_boxes  = (const float*)d_in[3];
    const int*   tn       = (const int*)d_in[4];
    float* out = (float*)d_out;

    char* ws = (char*)d_ws;
    int*    conf0    = (int*)(ws);              // 16 i32        @ 0
    float4* partials = (float4*)(ws + 64);      // 900 float4    @ 64
    float*  max_iou  = (float*)(ws + 14464);    // 14400 f32
    int*    max_idx  = (int*)(ws + 72064);      // 14400 i32
    float*  l1c0     = (float*)(ws + 129664);   // 14400 f32
    float*  giouc0   = (float*)(ws + 187264);   // 14400 f32

    k1_box<<<dim3(29, 16), 256, 0, stream>>>(s_boxes, t_boxes, t_logits,
                                             max_iou, max_idx, l1c0, giouc0, conf0);
    k2_cls<<<900, 256, 0, stream>>>(s_logits, t_logits, max_idx, max_iou,
                                    l1c0, giouc0, conf0, partials);
    k3_final<<<1, 256, 0, stream>>>(partials, tn, out);
}